// Round 5
// baseline (345.283 us; speedup 1.0000x reference)
//
#include <hip/hip_runtime.h>
#include <hip/hip_bf16.h>
#include <math.h>

#define T_CTX 2048
#define DM    2048
#define NQ    32
#define NKV   8
#define HD    64
#define QKV_LD 3072   // fused [T][Q(2048) | K(512) | V(512)] bf16

typedef __attribute__((ext_vector_type(8))) short short8;     // 8 bf16 = 4 VGPR
typedef __attribute__((ext_vector_type(4))) float floatx4;    // MFMA acc

// global -> LDS direct copy, 16B per lane. LDS dest must be wave-uniform base
// (HW writes lane i at base + i*16); global src is per-lane (rule #21: source
// carries the inverse swizzle, LDS stays linear, reads apply the swizzle).
__device__ __forceinline__ void gload_lds16(const void* g, void* l) {
  __builtin_amdgcn_global_load_lds(
      (const __attribute__((address_space(1))) void*)g,
      (__attribute__((address_space(3))) void*)l, 16, 0, 0);
}

// ---------------------------------------------------------------------------
// cast f32 -> bf16, 8 elems/thread
// ---------------------------------------------------------------------------
__global__ __launch_bounds__(256) void cast_bf16_kernel(const float* __restrict__ src,
                                                        __hip_bfloat16* __restrict__ dst) {
  const int i = blockIdx.x * 256 + threadIdx.x;
  const float4 a = ((const float4*)src)[2 * i];
  const float4 b = ((const float4*)src)[2 * i + 1];
  union { ushort u[8]; short8 v; } o;
  __hip_bfloat16 h;
  h = __float2bfloat16(a.x); o.u[0] = *(ushort*)&h;
  h = __float2bfloat16(a.y); o.u[1] = *(ushort*)&h;
  h = __float2bfloat16(a.z); o.u[2] = *(ushort*)&h;
  h = __float2bfloat16(a.w); o.u[3] = *(ushort*)&h;
  h = __float2bfloat16(b.x); o.u[4] = *(ushort*)&h;
  h = __float2bfloat16(b.y); o.u[5] = *(ushort*)&h;
  h = __float2bfloat16(b.z); o.u[6] = *(ushort*)&h;
  h = __float2bfloat16(b.w); o.u[7] = *(ushort*)&h;
  ((short8*)dst)[i] = o.v;
}

// ---------------------------------------------------------------------------
// transpose + cast: src f32 [Krows][Ncols] -> dst bf16 [Ncols][Krows]
// ---------------------------------------------------------------------------
__global__ __launch_bounds__(256) void transpose_cast_kernel(
    const float* __restrict__ src, __hip_bfloat16* __restrict__ dst,
    int Ncols, int Krows) {
  __shared__ float tile[64][65];
  const int n0 = blockIdx.x * 64;
  const int k0 = blockIdx.y * 64;
  const int c = threadIdx.x & 63;
  const int r0 = threadIdx.x >> 6;
#pragma unroll
  for (int s = 0; s < 16; ++s) {
    int r = r0 + 4 * s;
    tile[r][c] = src[(size_t)(k0 + r) * Ncols + n0 + c];
  }
  __syncthreads();
#pragma unroll
  for (int s = 0; s < 16; ++s) {
    int r = r0 + 4 * s;
    dst[(size_t)(n0 + r) * Krows + k0 + c] = __float2bfloat16(tile[c][r]);
  }
}

// ---------------------------------------------------------------------------
// bf16 MFMA GEMM (structure verified R3/R4): C = A[M][K] @ Bt[N][K]^T + bias.
// NEW: staging via global_load_lds dwordx4 — linear LDS dest, pre-swizzled
// global source (XOR involution matches the fragment-read swizzle).
// ---------------------------------------------------------------------------
template <typename OutT>
__global__ __launch_bounds__(256) void gemm_mfma_bt(
    const __hip_bfloat16* __restrict__ A, const __hip_bfloat16* __restrict__ Bt,
    const float* __restrict__ bias, OutT* __restrict__ C, int K, int ldc) {
  __shared__ alignas(16) short As[128 * 64];
  __shared__ alignas(16) short Bs[128 * 64];
  const int tid = threadIdx.x;
  const int lane = tid & 63;
  const int w = tid >> 6;
  const int wr = w >> 1, wc = w & 1;
  const int bm = blockIdx.y * 128, bn = blockIdx.x * 128;

  floatx4 acc[4][4];
#pragma unroll
  for (int m = 0; m < 4; ++m)
#pragma unroll
    for (int n = 0; n < 4; ++n) acc[m][n] = floatx4{0.f, 0.f, 0.f, 0.f};

  const int frag_kb = (lane >> 4) * 16;
  const int srow_in8 = lane >> 3;          // 0..7: row within the 8-row chunk
  const int sbyte = (lane & 7) * 16;       // 0..112: byte within 128B row

  for (int k0 = 0; k0 < K; k0 += 64) {
    __syncthreads();
#pragma unroll
    for (int i = 0; i < 4; ++i) {
      const int r = w * 32 + i * 8 + srow_in8;
      const int gcb = sbyte ^ ((r & 7) << 4);   // inverse-swizzled source col
      gload_lds16((const char*)(A + (size_t)(bm + r) * K + k0) + gcb,
                  (char*)As + (w * 32 + i * 8) * 128);
      gload_lds16((const char*)(Bt + (size_t)(bn + r) * K + k0) + gcb,
                  (char*)Bs + (w * 32 + i * 8) * 128);
    }
    __syncthreads();
#pragma unroll
    for (int h = 0; h < 2; ++h) {
      short8 af[4], bf[4];
      const int kb = h * 64 + frag_kb;
#pragma unroll
      for (int m = 0; m < 4; ++m) {
        const int ar = wr * 64 + m * 16 + (lane & 15);
        af[m] = *(const short8*)((const char*)As + ar * 128 + (kb ^ ((ar & 7) << 4)));
      }
#pragma unroll
      for (int n = 0; n < 4; ++n) {
        const int br = wc * 64 + n * 16 + (lane & 15);
        bf[n] = *(const short8*)((const char*)Bs + br * 128 + (kb ^ ((br & 7) << 4)));
      }
#pragma unroll
      for (int m = 0; m < 4; ++m)
#pragma unroll
        for (int n = 0; n < 4; ++n)
          acc[m][n] = __builtin_amdgcn_mfma_f32_16x16x32_bf16(af[m], bf[n], acc[m][n], 0, 0, 0);
    }
  }

  const int col_l = lane & 15;
  const int row_l = (lane >> 4) * 4;
#pragma unroll
  for (int n = 0; n < 4; ++n) {
    const int col = bn + wc * 64 + n * 16 + col_l;
    const float bv = bias[col];
#pragma unroll
    for (int m = 0; m < 4; ++m) {
      const int row0 = bm + wr * 64 + m * 16 + row_l;
#pragma unroll
      for (int r2 = 0; r2 < 4; ++r2) {
        const float v = acc[m][n][r2] + bv;
        if constexpr (sizeof(OutT) == 2)
          C[(size_t)(row0 + r2) * ldc + col] = __float2bfloat16(v);
        else
          C[(size_t)(row0 + r2) * ldc + col] = v;
      }
    }
  }
}

// ---------------------------------------------------------------------------
// RoPE in-place on bf16 qkv. Q heads additionally scaled by 0.125 (exact).
// ---------------------------------------------------------------------------
__global__ __launch_bounds__(256) void rope_kernel(__hip_bfloat16* __restrict__ qkv,
                                                   const float* __restrict__ freqs) {
  const int idx = blockIdx.x * 256 + threadIdx.x;
  const int i = idx & 31;
  const int h = (idx >> 5) % 40;
  const int t = idx / (40 * 32);
  const int base = (h < 32) ? h * HD : DM + (h - 32) * HD;
  __hip_bfloat16* p = qkv + (size_t)t * QKV_LD + base;
  const float f = freqs[t * 32 + i];
  float s, c;
  sincosf(f, &s, &c);
  const float x1 = __bfloat162float(p[i]);
  const float x2 = __bfloat162float(p[i + 32]);
  float r1 = x1 * c - x2 * s;
  float r2 = x1 * s + x2 * c;
  if (h < 32) { r1 *= 0.125f; r2 *= 0.125f; }
  p[i]      = __float2bfloat16(r1);
  p[i + 32] = __float2bfloat16(r2);
}

// ---------------------------------------------------------------------------
// MFMA flash attention. Block = (head, 64-row Q block): grid NQ*32 = 1024,
// 4 waves x 16 rows. K staged via global_load_lds (pre-swizzled source);
// V^T reg-staged transpose; per-wave P buffer. Fragment conventions identical
// to gemm_mfma_bt (verified R4): A/B row = lane&15, k-slice (lane>>4)*8;
// C/D col = lane&15, row = (lane>>4)*4 + reg.
// ---------------------------------------------------------------------------
__global__ __launch_bounds__(256) void attn_mfma_kernel(
    const __hip_bfloat16* __restrict__ qkv, __hip_bfloat16* __restrict__ O) {
  const int bid = blockIdx.x;
  const int head = bid >> 5;
  const int qb = 31 - (bid & 31);     // LJF: heavy q-blocks dispatch first
  const int kvh = head >> 2;
  const int tid = threadIdx.x;
  const int lane = tid & 63;
  const int w = tid >> 6;
  const int l15 = lane & 15;
  const int lg = lane >> 4;
  const int qbase = qb * 64 + w * 16;   // this wave's first q row

  __shared__ alignas(16) char Ks[64 * 128];     // bf16 [64 s][64 d] swizzled
  __shared__ alignas(16) char Vts[64 * 128];    // bf16 [64 d][64 s] swizzled
  __shared__ alignas(16) char Ps[4][16 * 128];  // per-wave P [16][64] swizzled

  // Q fragments: row = qbase + l15, d = kh*32 + lg*8 .. +8
  short8 qf[2];
#pragma unroll
  for (int kh = 0; kh < 2; ++kh)
    qf[kh] = *(const short8*)(qkv + (size_t)(qbase + l15) * QKV_LD +
                              head * HD + kh * 32 + lg * 8);

  floatx4 o_acc[4];
  float mrow[4], lrow[4];
#pragma unroll
  for (int n = 0; n < 4; ++n) o_acc[n] = floatx4{0.f, 0.f, 0.f, 0.f};
#pragma unroll
  for (int r = 0; r < 4; ++r) { mrow[r] = -INFINITY; lrow[r] = 0.f; }

  const __hip_bfloat16* Kg = qkv + DM + kvh * HD;
  const __hip_bfloat16* Vg = qkv + DM + NKV * HD + kvh * HD;
  const int nt = qb + 1;
  const int srow_in8 = lane >> 3;
  const int sbyte = (lane & 7) * 16;

  for (int kt = 0; kt < nt; ++kt) {
    const int s0 = kt * 64;
    __syncthreads();
    // --- stage K tile via global_load_lds: 2 calls/wave, 8 rows each ---
#pragma unroll
    for (int i = 0; i < 2; ++i) {
      const int r = w * 16 + i * 8 + srow_in8;
      const int gcb = sbyte ^ ((r & 7) << 4);
      gload_lds16((const char*)(Kg + (size_t)(s0 + r) * QKV_LD) + gcb,
                  Ks + (w * 16 + i * 8) * 128);
    }
    // --- stage V^T: thread handles s = tid&63, d0 = (tid>>6)*16 ---
    {
      const int vs = tid & 63, d0 = (tid >> 6) * 16;
      const short8 va = *(const short8*)(Vg + (size_t)(s0 + vs) * QKV_LD + d0);
      const short8 vb = *(const short8*)(Vg + (size_t)(s0 + vs) * QKV_LD + d0 + 8);
#pragma unroll
      for (int j = 0; j < 8; ++j) {
        const int rd = d0 + j;
        *(short*)(Vts + rd * 128 + ((vs * 2) ^ ((rd & 7) << 4))) = va[j];
      }
#pragma unroll
      for (int j = 0; j < 8; ++j) {
        const int rd = d0 + 8 + j;
        *(short*)(Vts + rd * 128 + ((vs * 2) ^ ((rd & 7) << 4))) = vb[j];
      }
    }
    __syncthreads();

    // --- QK^T: S[16][64] ---
    floatx4 sacc[4];
#pragma unroll
    for (int n = 0; n < 4; ++n) sacc[n] = floatx4{0.f, 0.f, 0.f, 0.f};
#pragma unroll
    for (int kh = 0; kh < 2; ++kh) {
      short8 bf[4];
#pragma unroll
      for (int n = 0; n < 4; ++n) {
        const int kr = n * 16 + l15;
        bf[n] = *(const short8*)(Ks + kr * 128 + ((kh * 64 + lg * 16) ^ ((kr & 7) << 4)));
      }
#pragma unroll
      for (int n = 0; n < 4; ++n)
        sacc[n] = __builtin_amdgcn_mfma_f32_16x16x32_bf16(qf[kh], bf[n], sacc[n], 0, 0, 0);
    }
    // --- causal mask (tiles overlapping this wave's diagonal) ---
    if (s0 + 63 > qbase) {
#pragma unroll
      for (int n = 0; n < 4; ++n)
#pragma unroll
        for (int r = 0; r < 4; ++r)
          if (s0 + n * 16 + l15 > qbase + lg * 4 + r)
            sacc[n][r] = -INFINITY;
    }
    // --- online softmax (rows prow = lg*4 + r) ---
#pragma unroll
    for (int r = 0; r < 4; ++r) {
      float t = fmaxf(fmaxf(sacc[0][r], sacc[1][r]), fmaxf(sacc[2][r], sacc[3][r]));
      t = fmaxf(t, __shfl_xor(t, 1));
      t = fmaxf(t, __shfl_xor(t, 2));
      t = fmaxf(t, __shfl_xor(t, 4));
      t = fmaxf(t, __shfl_xor(t, 8));
      const float mn = fmaxf(mrow[r], t);
      const float corr = __expf(mrow[r] - mn);   // -inf first tile -> 0
      mrow[r] = mn;
      float pv[4];
      float ls = 0.f;
#pragma unroll
      for (int n = 0; n < 4; ++n) {
        pv[n] = __expf(sacc[n][r] - mn);         // masked -inf -> 0
        ls += pv[n];
      }
      ls += __shfl_xor(ls, 1);
      ls += __shfl_xor(ls, 2);
      ls += __shfl_xor(ls, 4);
      ls += __shfl_xor(ls, 8);
      lrow[r] = lrow[r] * corr + ls;
#pragma unroll
      for (int n = 0; n < 4; ++n) o_acc[n][r] *= corr;
      const int prow = lg * 4 + r;
#pragma unroll
      for (int n = 0; n < 4; ++n)
        *(__hip_bfloat16*)(Ps[w] + prow * 128 +
                           (((n * 16 + l15) * 2) ^ ((prow & 7) << 4))) =
            __float2bfloat16(pv[n]);
    }
    // --- PV: O[16][64] += P @ V (same-wave P buffer, no barrier needed) ---
#pragma unroll
    for (int kh = 0; kh < 2; ++kh) {
      const int pr = l15;
      const short8 pf = *(const short8*)(Ps[w] + pr * 128 +
                                         ((kh * 64 + lg * 16) ^ ((pr & 7) << 4)));
      short8 vf[4];
#pragma unroll
      for (int n = 0; n < 4; ++n) {
        const int vr = n * 16 + l15;
        vf[n] = *(const short8*)(Vts + vr * 128 + ((kh * 64 + lg * 16) ^ ((vr & 7) << 4)));
      }
#pragma unroll
      for (int n = 0; n < 4; ++n)
        o_acc[n] = __builtin_amdgcn_mfma_f32_16x16x32_bf16(pf, vf[n], o_acc[n], 0, 0, 0);
    }
  }

  // --- epilogue ---
  float inv[4];
#pragma unroll
  for (int r = 0; r < 4; ++r) inv[r] = 1.f / lrow[r];
#pragma unroll
  for (int n = 0; n < 4; ++n)
#pragma unroll
    for (int r = 0; r < 4; ++r)
      O[(size_t)(qbase + lg * 4 + r) * DM + head * HD + n * 16 + l15] =
          __float2bfloat16(o_acc[n][r] * inv[r]);
}

// ---------------------------------------------------------------------------
extern "C" void kernel_launch(void* const* d_in, const int* in_sizes, int n_in,
                              void* d_out, int out_size, void* d_ws, size_t ws_size,
                              hipStream_t stream) {
  const float* x     = (const float*)d_in[0];
  const float* Wq    = (const float*)d_in[1];
  const float* bq    = (const float*)d_in[2];
  const float* Wk    = (const float*)d_in[3];
  const float* bk    = (const float*)d_in[4];
  const float* Wv    = (const float*)d_in[5];
  const float* bv    = (const float*)d_in[6];
  const float* Wo    = (const float*)d_in[7];
  const float* bo    = (const float*)d_in[8];
  const float* freqs = (const float*)d_in[9];
  float* out = (float*)d_out;

  // ws layout (peak 33.6 MB):
  //   [0)           qkv bf16 [2048][3072]            12,582,912 B
  //   [12,582,912)  wt  bf16 [3072][2048] (QKV^T)    12,582,912 B  -> reused for Wo^T
  //   [25,165,824)  xb  bf16 [2048][2048]             8,388,608 B  -> reused for attn out
  //   [33,554,432)  bias_cat f32 [3072]                   12,288 B
  char* ws = (char*)d_ws;
  __hip_bfloat16* qkv  = (__hip_bfloat16*)ws;
  __hip_bfloat16* wt   = (__hip_bfloat16*)(ws + 12582912);
  __hip_bfloat16* xb   = (__hip_bfloat16*)(ws + 25165824);
  __hip_bfloat16* obuf = xb;   // alias: xb dead after QKV GEMM
  __hip_bfloat16* wot  = wt;   // alias: wt dead after QKV GEMM
  float*          bcat = (float*)(ws + 33554432);

  const dim3 blk(256);

  cast_bf16_kernel<<<(DM * T_CTX) / (256 * 8), blk, 0, stream>>>(x, xb);
  transpose_cast_kernel<<<dim3(32, 32), blk, 0, stream>>>(Wq, wt, 2048, 2048);
  transpose_cast_kernel<<<dim3(8, 32),  blk, 0, stream>>>(Wk, wt + (size_t)2048 * 2048, 512, 2048);
  transpose_cast_kernel<<<dim3(8, 32),  blk, 0, stream>>>(Wv, wt + (size_t)2560 * 2048, 512, 2048);
  hipMemcpyAsync(bcat,        bq, 2048 * 4, hipMemcpyDeviceToDevice, stream);
  hipMemcpyAsync(bcat + 2048, bk, 512 * 4,  hipMemcpyDeviceToDevice, stream);
  hipMemcpyAsync(bcat + 2560, bv, 512 * 4,  hipMemcpyDeviceToDevice, stream);

  // fused QKV projection -> bf16 qkv (ldc 3072)
  gemm_mfma_bt<__hip_bfloat16><<<dim3(3072 / 128, 2048 / 128), blk, 0, stream>>>(
      xb, wt, bcat, qkv, DM, QKV_LD);

  // RoPE (bf16 in place; Q scaled by 2^-3)
  rope_kernel<<<(T_CTX * 40 * 32) / 256, blk, 0, stream>>>(qkv, freqs);

  // Wo^T (reuses wt region)
  transpose_cast_kernel<<<dim3(32, 32), blk, 0, stream>>>(Wo, wot, 2048, 2048);

  // MFMA flash attention -> obuf bf16 [2048][2048]
  attn_mfma_kernel<<<dim3(NQ * 32), blk, 0, stream>>>(qkv, obuf);

  // output projection -> d_out (f32)
  gemm_mfma_bt<float><<<dim3(2048 / 128, 2048 / 128), blk, 0, stream>>>(
      obuf, wot, bo, out, DM, DM);
}

// Round 6
// 314.771 us; speedup vs baseline: 1.0969x; 1.0969x over previous
//
#include <hip/hip_runtime.h>
#include <hip/hip_bf16.h>
#include <math.h>

#define T_CTX 2048
#define DM    2048
#define NQ    32
#define NKV   8
#define HD    64
#define QKV_LD 3072   // fused [T][Q(2048) | K(512) | V(512)] bf16

typedef __attribute__((ext_vector_type(8))) short short8;     // 8 bf16 = 4 VGPR
typedef __attribute__((ext_vector_type(4))) float floatx4;    // MFMA acc

// global -> LDS direct copy, 16B/lane. LDS dest wave-uniform base (HW: lane i
// writes base + i*16); global src per-lane, carries the inverse swizzle
// (rule #21: linear LDS, pre-swizzled source, swizzled read).
__device__ __forceinline__ void gload_lds16(const void* g, void* l) {
  __builtin_amdgcn_global_load_lds(
      (const __attribute__((address_space(1))) void*)g,
      (__attribute__((address_space(3))) void*)l, 16, 0, 0);
}

// ---------------------------------------------------------------------------
// Fused prep: x cast (blocks 0..2047), Wq^T (2048..3071), Wk^T (3072..3327),
// Wv^T (3328..3583), Wo^T (3584..4607), bias concat (4608). One launch.
// ---------------------------------------------------------------------------
__device__ __forceinline__ void tcast_body(const float* __restrict__ src,
                                           __hip_bfloat16* __restrict__ dst,
                                           int Ncols, int Krows, int bx, int by,
                                           int tid, float (*tile)[66]) {
  const int n0 = bx * 64, k0 = by * 64;
  const int c = tid & 63, r0 = tid >> 6;
#pragma unroll
  for (int s = 0; s < 16; ++s) {
    int r = r0 + 4 * s;
    tile[r][c] = src[(size_t)(k0 + r) * Ncols + n0 + c];
  }
  __syncthreads();
#pragma unroll
  for (int s = 0; s < 16; ++s) {
    int r = r0 + 4 * s;
    dst[(size_t)(n0 + r) * Krows + k0 + c] = __float2bfloat16(tile[c][r]);
  }
}

__global__ __launch_bounds__(256) void prep_kernel(
    const float* __restrict__ x, const float* __restrict__ Wq,
    const float* __restrict__ Wk, const float* __restrict__ Wv,
    const float* __restrict__ Wo, const float* __restrict__ bq,
    const float* __restrict__ bk, const float* __restrict__ bv,
    __hip_bfloat16* __restrict__ xb, __hip_bfloat16* __restrict__ wt,
    __hip_bfloat16* __restrict__ wot, float* __restrict__ bcat) {
  __shared__ float tile[64][66];
  const int bid = blockIdx.x;
  const int tid = threadIdx.x;
  if (bid < 2048) {                    // cast x -> bf16, 8 elems/thread
    const int i = bid * 256 + tid;
    const float4 a = ((const float4*)x)[2 * i];
    const float4 b = ((const float4*)x)[2 * i + 1];
    union { ushort u[8]; short8 v; } o;
    __hip_bfloat16 h;
    h = __float2bfloat16(a.x); o.u[0] = *(ushort*)&h;
    h = __float2bfloat16(a.y); o.u[1] = *(ushort*)&h;
    h = __float2bfloat16(a.z); o.u[2] = *(ushort*)&h;
    h = __float2bfloat16(a.w); o.u[3] = *(ushort*)&h;
    h = __float2bfloat16(b.x); o.u[4] = *(ushort*)&h;
    h = __float2bfloat16(b.y); o.u[5] = *(ushort*)&h;
    h = __float2bfloat16(b.z); o.u[6] = *(ushort*)&h;
    h = __float2bfloat16(b.w); o.u[7] = *(ushort*)&h;
    ((short8*)xb)[i] = o.v;
  } else if (bid < 3072) {             // Wq^T [2048x2048]
    const int lid = bid - 2048;
    tcast_body(Wq, wt, 2048, 2048, lid & 31, lid >> 5, tid, tile);
  } else if (bid < 3328) {             // Wk^T [2048x512] -> wt + 2048*2048
    const int lid = bid - 3072;
    tcast_body(Wk, wt + (size_t)2048 * 2048, 512, 2048, lid & 7, lid >> 3, tid, tile);
  } else if (bid < 3584) {             // Wv^T -> wt + 2560*2048
    const int lid = bid - 3328;
    tcast_body(Wv, wt + (size_t)2560 * 2048, 512, 2048, lid & 7, lid >> 3, tid, tile);
  } else if (bid < 4608) {             // Wo^T [2048x2048] -> wot
    const int lid = bid - 3584;
    tcast_body(Wo, wot, 2048, 2048, lid & 31, lid >> 5, tid, tile);
  } else {                             // bias concat
    for (int i = tid; i < 3072; i += 256)
      bcat[i] = (i < 2048) ? bq[i] : ((i < 2560) ? bk[i - 2048] : bv[i - 2560]);
  }
}

// ---------------------------------------------------------------------------
// bf16 MFMA GEMM (verified R3-R5): C = A[M][K] @ Bt[N][K]^T + bias.
// global_load_lds staging, linear LDS dest + pre-swizzled source.
// ---------------------------------------------------------------------------
template <typename OutT>
__global__ __launch_bounds__(256) void gemm_mfma_bt(
    const __hip_bfloat16* __restrict__ A, const __hip_bfloat16* __restrict__ Bt,
    const float* __restrict__ bias, OutT* __restrict__ C, int K, int ldc) {
  __shared__ alignas(16) short As[128 * 64];
  __shared__ alignas(16) short Bs[128 * 64];
  const int tid = threadIdx.x;
  const int lane = tid & 63;
  const int w = tid >> 6;
  const int wr = w >> 1, wc = w & 1;
  const int bm = blockIdx.y * 128, bn = blockIdx.x * 128;

  floatx4 acc[4][4];
#pragma unroll
  for (int m = 0; m < 4; ++m)
#pragma unroll
    for (int n = 0; n < 4; ++n) acc[m][n] = floatx4{0.f, 0.f, 0.f, 0.f};

  const int frag_kb = (lane >> 4) * 16;
  const int srow_in8 = lane >> 3;
  const int sbyte = (lane & 7) * 16;

  for (int k0 = 0; k0 < K; k0 += 64) {
    __syncthreads();
#pragma unroll
    for (int i = 0; i < 4; ++i) {
      const int r = w * 32 + i * 8 + srow_in8;
      const int gcb = sbyte ^ ((r & 7) << 4);
      gload_lds16((const char*)(A + (size_t)(bm + r) * K + k0) + gcb,
                  (char*)As + (w * 32 + i * 8) * 128);
      gload_lds16((const char*)(Bt + (size_t)(bn + r) * K + k0) + gcb,
                  (char*)Bs + (w * 32 + i * 8) * 128);
    }
    __syncthreads();
#pragma unroll
    for (int h = 0; h < 2; ++h) {
      short8 af[4], bf[4];
      const int kb = h * 64 + frag_kb;
#pragma unroll
      for (int m = 0; m < 4; ++m) {
        const int ar = wr * 64 + m * 16 + (lane & 15);
        af[m] = *(const short8*)((const char*)As + ar * 128 + (kb ^ ((ar & 7) << 4)));
      }
#pragma unroll
      for (int n = 0; n < 4; ++n) {
        const int br = wc * 64 + n * 16 + (lane & 15);
        bf[n] = *(const short8*)((const char*)Bs + br * 128 + (kb ^ ((br & 7) << 4)));
      }
#pragma unroll
      for (int m = 0; m < 4; ++m)
#pragma unroll
        for (int n = 0; n < 4; ++n)
          acc[m][n] = __builtin_amdgcn_mfma_f32_16x16x32_bf16(af[m], bf[n], acc[m][n], 0, 0, 0);
    }
  }

  const int col_l = lane & 15;
  const int row_l = (lane >> 4) * 4;
#pragma unroll
  for (int n = 0; n < 4; ++n) {
    const int col = bn + wc * 64 + n * 16 + col_l;
    const float bv = bias[col];
#pragma unroll
    for (int m = 0; m < 4; ++m) {
      const int row0 = bm + wr * 64 + m * 16 + row_l;
#pragma unroll
      for (int r2 = 0; r2 < 4; ++r2) {
        const float v = acc[m][n][r2] + bv;
        if constexpr (sizeof(OutT) == 2)
          C[(size_t)(row0 + r2) * ldc + col] = __float2bfloat16(v);
        else
          C[(size_t)(row0 + r2) * ldc + col] = v;
      }
    }
  }
}

// ---------------------------------------------------------------------------
// RoPE in-place on bf16 qkv. Q heads scaled by 0.125 (exact in bf16).
// ---------------------------------------------------------------------------
__global__ __launch_bounds__(256) void rope_kernel(__hip_bfloat16* __restrict__ qkv,
                                                   const float* __restrict__ freqs) {
  const int idx = blockIdx.x * 256 + threadIdx.x;
  const int i = idx & 31;
  const int h = (idx >> 5) % 40;
  const int t = idx / (40 * 32);
  const int base = (h < 32) ? h * HD : DM + (h - 32) * HD;
  __hip_bfloat16* p = qkv + (size_t)t * QKV_LD + base;
  const float f = freqs[t * 32 + i];
  float s, c;
  sincosf(f, &s, &c);
  const float x1 = __bfloat162float(p[i]);
  const float x2 = __bfloat162float(p[i + 32]);
  float r1 = x1 * c - x2 * s;
  float r2 = x1 * s + x2 * c;
  if (h < 32) { r1 *= 0.125f; r2 *= 0.125f; }
  p[i]      = __float2bfloat16(r1);
  p[i + 32] = __float2bfloat16(r2);
}

// ---------------------------------------------------------------------------
// V^T precompute: qkv V-cols [2048 t][512 (kvh,d)] -> vt [512][2048 t].
// ---------------------------------------------------------------------------
__global__ __launch_bounds__(256) void transpose_v_kernel(
    const __hip_bfloat16* __restrict__ qkv, __hip_bfloat16* __restrict__ vt) {
  __shared__ short tile[64][66];
  const int c0 = blockIdx.x * 64;   // V column (kvh*64+d), 0..511
  const int t0 = blockIdx.y * 64;   // time
  const int c = threadIdx.x & 63;
  const int r0 = threadIdx.x >> 6;
#pragma unroll
  for (int s = 0; s < 16; ++s) {
    int r = r0 + 4 * s;
    tile[r][c] = *(const short*)(qkv + (size_t)(t0 + r) * QKV_LD + DM + NKV * HD + c0 + c);
  }
  __syncthreads();
#pragma unroll
  for (int s = 0; s < 16; ++s) {
    int r = r0 + 4 * s;
    *(short*)(vt + (size_t)(c0 + r) * T_CTX + t0 + c) = tile[c][r];
  }
}

// ---------------------------------------------------------------------------
// MFMA flash attention. Block = (head-pair, 64-row Q block): grid 16*32=512,
// 4 waves x 16 rows x 2 heads (heads share kv-head -> shared K/V staging and
// shared bf/vf fragment reads). K and V^T staged via global_load_lds.
// Defer-max online softmax (THR=8). Fragment conventions as verified:
// A/B row = lane&15, k-slice (lane>>4)*8; C/D col = lane&15, row=(lane>>4)*4+r.
// ---------------------------------------------------------------------------
__global__ __launch_bounds__(256) void attn_mfma_kernel(
    const __hip_bfloat16* __restrict__ qkv, const __hip_bfloat16* __restrict__ vtg,
    __hip_bfloat16* __restrict__ O) {
  const int bid = blockIdx.x;
  const int hp = bid >> 5;            // head pair 0..15
  const int qb = 31 - (bid & 31);     // LJF: heavy q-blocks first
  const int h0 = hp * 2;
  const int kvh = h0 >> 2;
  const int tid = threadIdx.x;
  const int lane = tid & 63;
  const int w = tid >> 6;
  const int l15 = lane & 15;
  const int lg = lane >> 4;
  const int qbase = qb * 64 + w * 16;   // this wave's first q row

  __shared__ alignas(16) char Ks[64 * 128];       // bf16 [64 s][64 d] swizzled
  __shared__ alignas(16) char Vts[64 * 128];      // bf16 [64 d][64 s] swizzled
  __shared__ alignas(16) char Ps[4][2][16 * 128]; // per-wave, per-head P

  // Q fragments: row = qbase + l15, d = kh*32 + lg*8 .. +8
  short8 qf[2][2];
#pragma unroll
  for (int hh = 0; hh < 2; ++hh)
#pragma unroll
    for (int kh = 0; kh < 2; ++kh)
      qf[hh][kh] = *(const short8*)(qkv + (size_t)(qbase + l15) * QKV_LD +
                                    (h0 + hh) * HD + kh * 32 + lg * 8);

  floatx4 o_acc[2][4];
  float mrow[2][4], lrow[2][4];
#pragma unroll
  for (int hh = 0; hh < 2; ++hh)
#pragma unroll
    for (int n = 0; n < 4; ++n) o_acc[hh][n] = floatx4{0.f, 0.f, 0.f, 0.f};
#pragma unroll
  for (int hh = 0; hh < 2; ++hh)
#pragma unroll
    for (int r = 0; r < 4; ++r) { mrow[hh][r] = -INFINITY; lrow[hh][r] = 0.f; }

  const __hip_bfloat16* Kg = qkv + DM + kvh * HD;
  const int nt = qb + 1;
  const int srow_in8 = lane >> 3;
  const int sbyte = (lane & 7) * 16;

  for (int kt = 0; kt < nt; ++kt) {
    const int s0 = kt * 64;
    __syncthreads();
    // --- stage K rows + V^T rows via global_load_lds (2+2 calls/wave) ---
#pragma unroll
    for (int i = 0; i < 2; ++i) {
      const int r = w * 16 + i * 8 + srow_in8;
      const int gcb = sbyte ^ ((r & 7) << 4);
      gload_lds16((const char*)(Kg + (size_t)(s0 + r) * QKV_LD) + gcb,
                  Ks + (w * 16 + i * 8) * 128);
      gload_lds16((const char*)(vtg + (size_t)(kvh * 64 + r) * T_CTX + s0) + gcb,
                  Vts + (w * 16 + i * 8) * 128);
    }
    __syncthreads();

    if (s0 > qbase + 15) continue;   // tile fully above this wave's rows

    // --- QK^T: S[16][64] for both heads (shared K fragments) ---
    floatx4 sacc[2][4];
#pragma unroll
    for (int hh = 0; hh < 2; ++hh)
#pragma unroll
      for (int n = 0; n < 4; ++n) sacc[hh][n] = floatx4{0.f, 0.f, 0.f, 0.f};
#pragma unroll
    for (int kh = 0; kh < 2; ++kh) {
      short8 bf[4];
#pragma unroll
      for (int n = 0; n < 4; ++n) {
        const int kr = n * 16 + l15;
        bf[n] = *(const short8*)(Ks + kr * 128 + ((kh * 64 + lg * 16) ^ ((kr & 7) << 4)));
      }
#pragma unroll
      for (int hh = 0; hh < 2; ++hh)
#pragma unroll
        for (int n = 0; n < 4; ++n)
          sacc[hh][n] = __builtin_amdgcn_mfma_f32_16x16x32_bf16(qf[hh][kh], bf[n], sacc[hh][n], 0, 0, 0);
    }
    // --- causal mask (same predicate for both heads) ---
    if (s0 + 63 > qbase) {
#pragma unroll
      for (int n = 0; n < 4; ++n)
#pragma unroll
        for (int r = 0; r < 4; ++r)
          if (s0 + n * 16 + l15 > qbase + lg * 4 + r) {
            sacc[0][n][r] = -INFINITY;
            sacc[1][n][r] = -INFINITY;
          }
    }
    // --- defer-max online softmax + P writes ---
#pragma unroll
    for (int hh = 0; hh < 2; ++hh) {
#pragma unroll
      for (int r = 0; r < 4; ++r) {
        float t = fmaxf(fmaxf(sacc[hh][0][r], sacc[hh][1][r]),
                        fmaxf(sacc[hh][2][r], sacc[hh][3][r]));
        t = fmaxf(t, __shfl_xor(t, 1));
        t = fmaxf(t, __shfl_xor(t, 2));
        t = fmaxf(t, __shfl_xor(t, 4));
        t = fmaxf(t, __shfl_xor(t, 8));
        float mn = mrow[hh][r];
        if (t > mn + 8.f) {            // rescale only on real max growth (T13)
          const float corr = __expf(mn - t);   // mn=-inf first tile -> 0
          lrow[hh][r] *= corr;
#pragma unroll
          for (int n = 0; n < 4; ++n) o_acc[hh][n][r] *= corr;
          mn = t;
          mrow[hh][r] = t;
        }
        float pv[4];
        float ls = 0.f;
#pragma unroll
        for (int n = 0; n < 4; ++n) {
          pv[n] = __expf(sacc[hh][n][r] - mn);   // bounded by e^8
          ls += pv[n];
        }
        ls += __shfl_xor(ls, 1);
        ls += __shfl_xor(ls, 2);
        ls += __shfl_xor(ls, 4);
        ls += __shfl_xor(ls, 8);
        lrow[hh][r] += ls;
        const int prow = lg * 4 + r;
#pragma unroll
        for (int n = 0; n < 4; ++n)
          *(__hip_bfloat16*)(Ps[w][hh] + prow * 128 +
                             (((n * 16 + l15) * 2) ^ ((prow & 7) << 4))) =
              __float2bfloat16(pv[n]);
      }
    }
    // --- PV for both heads (shared V fragments) ---
#pragma unroll
    for (int kh = 0; kh < 2; ++kh) {
      short8 vf[4];
#pragma unroll
      for (int n = 0; n < 4; ++n) {
        const int vr = n * 16 + l15;
        vf[n] = *(const short8*)(Vts + vr * 128 + ((kh * 64 + lg * 16) ^ ((vr & 7) << 4)));
      }
#pragma unroll
      for (int hh = 0; hh < 2; ++hh) {
        const short8 pf = *(const short8*)(Ps[w][hh] + l15 * 128 +
                                           ((kh * 64 + lg * 16) ^ ((l15 & 7) << 4)));
#pragma unroll
        for (int n = 0; n < 4; ++n)
          o_acc[hh][n] = __builtin_amdgcn_mfma_f32_16x16x32_bf16(pf, vf[n], o_acc[hh][n], 0, 0, 0);
      }
    }
  }

  // --- epilogue ---
#pragma unroll
  for (int hh = 0; hh < 2; ++hh) {
    float inv[4];
#pragma unroll
    for (int r = 0; r < 4; ++r) inv[r] = 1.f / lrow[hh][r];
#pragma unroll
    for (int n = 0; n < 4; ++n)
#pragma unroll
      for (int r = 0; r < 4; ++r)
        O[(size_t)(qbase + lg * 4 + r) * DM + (h0 + hh) * HD + n * 16 + l15] =
            __float2bfloat16(o_acc[hh][n][r] * inv[r]);
  }
}

// ---------------------------------------------------------------------------
extern "C" void kernel_launch(void* const* d_in, const int* in_sizes, int n_in,
                              void* d_out, int out_size, void* d_ws, size_t ws_size,
                              hipStream_t stream) {
  const float* x     = (const float*)d_in[0];
  const float* Wq    = (const float*)d_in[1];
  const float* bq    = (const float*)d_in[2];
  const float* Wk    = (const float*)d_in[3];
  const float* bk    = (const float*)d_in[4];
  const float* Wv    = (const float*)d_in[5];
  const float* bv    = (const float*)d_in[6];
  const float* Wo    = (const float*)d_in[7];
  const float* bo    = (const float*)d_in[8];
  const float* freqs = (const float*)d_in[9];
  float* out = (float*)d_out;

  // ws layout (peak ~44.1 MB):
  //   [0)           qkv  bf16 [2048][3072]           12,582,912 B
  //   [12,582,912)  wt   bf16 [3072][2048] (QKV^T)   12,582,912 B
  //   [25,165,824)  xb   bf16 [2048][2048]            8,388,608 B -> attn out after QKV GEMM
  //   [33,554,432)  wot  bf16 [2048][2048] (Wo^T)     8,388,608 B
  //   [41,943,040)  vt   bf16 [512][2048]  (V^T)      2,097,152 B
  //   [44,040,192)  bcat f32 [3072]                      12,288 B
  char* ws = (char*)d_ws;
  __hip_bfloat16* qkv  = (__hip_bfloat16*)ws;
  __hip_bfloat16* wt   = (__hip_bfloat16*)(ws + 12582912);
  __hip_bfloat16* xb   = (__hip_bfloat16*)(ws + 25165824);
  __hip_bfloat16* obuf = xb;   // alias: xb dead after QKV GEMM
  __hip_bfloat16* wot  = (__hip_bfloat16*)(ws + 33554432);
  __hip_bfloat16* vt   = (__hip_bfloat16*)(ws + 41943040);
  float*          bcat = (float*)(ws + 44040192);

  const dim3 blk(256);

  // one fused prep launch: x cast + 4 weight transposes + bias concat
  prep_kernel<<<dim3(4609), blk, 0, stream>>>(x, Wq, Wk, Wv, Wo, bq, bk, bv,
                                              xb, wt, wot, bcat);

  // fused QKV projection -> bf16 qkv (ldc 3072)
  gemm_mfma_bt<__hip_bfloat16><<<dim3(3072 / 128, 2048 / 128), blk, 0, stream>>>(
      xb, wt, bcat, qkv, DM, QKV_LD);

  // RoPE (bf16 in place; Q scaled by 2^-3)
  rope_kernel<<<(T_CTX * 40 * 32) / 256, blk, 0, stream>>>(qkv, freqs);

  // V^T precompute (V untouched by rope)
  transpose_v_kernel<<<dim3(8, 32), blk, 0, stream>>>(qkv, vt);

  // MFMA flash attention -> obuf bf16 [2048][2048]
  attn_mfma_kernel<<<dim3(16 * 32), blk, 0, stream>>>(qkv, vt, obuf);

  // output projection -> d_out (f32)
  gemm_mfma_bt<float><<<dim3(2048 / 128, 2048 / 128), blk, 0, stream>>>(
      obuf, wot, bo, out, DM, DM);
}

// Round 7
// 302.028 us; speedup vs baseline: 1.1432x; 1.0422x over previous
//
#include <hip/hip_runtime.h>
#include <hip/hip_bf16.h>
#include <math.h>

#define T_CTX 2048
#define DM    2048
#define NQ    32
#define NKV   8
#define HD    64
#define QKV_LD 3072   // fused [T][Q(2048) | K(512) | V(512)] bf16

typedef __attribute__((ext_vector_type(8))) short short8;     // 8 bf16 = 4 VGPR
typedef __attribute__((ext_vector_type(4))) float floatx4;    // MFMA acc

// global -> LDS direct copy, 16B/lane. LDS dest wave-uniform base (HW: lane i
// writes base + i*16); global src per-lane, carries the inverse swizzle
// (rule #21: linear LDS, pre-swizzled source, swizzled read).
__device__ __forceinline__ void gload_lds16(const void* g, void* l) {
  __builtin_amdgcn_global_load_lds(
      (const __attribute__((address_space(1))) void*)g,
      (__attribute__((address_space(3))) void*)l, 16, 0, 0);
}

// ---------------------------------------------------------------------------
// Fused prep: x cast (blocks 0..2047), Wq^T (2048..3071), Wk^T (3072..3327),
// Wv^T (3328..3583), Wo^T (3584..4607), bias concat (4608). One launch.
// ---------------------------------------------------------------------------
__device__ __forceinline__ void tcast_body(const float* __restrict__ src,
                                           __hip_bfloat16* __restrict__ dst,
                                           int Ncols, int Krows, int bx, int by,
                                           int tid, float (*tile)[66]) {
  const int n0 = bx * 64, k0 = by * 64;
  const int c = tid & 63, r0 = tid >> 6;
#pragma unroll
  for (int s = 0; s < 16; ++s) {
    int r = r0 + 4 * s;
    tile[r][c] = src[(size_t)(k0 + r) * Ncols + n0 + c];
  }
  __syncthreads();
#pragma unroll
  for (int s = 0; s < 16; ++s) {
    int r = r0 + 4 * s;
    dst[(size_t)(n0 + r) * Krows + k0 + c] = __float2bfloat16(tile[c][r]);
  }
}

__global__ __launch_bounds__(256) void prep_kernel(
    const float* __restrict__ x, const float* __restrict__ Wq,
    const float* __restrict__ Wk, const float* __restrict__ Wv,
    const float* __restrict__ Wo, const float* __restrict__ bq,
    const float* __restrict__ bk, const float* __restrict__ bv,
    __hip_bfloat16* __restrict__ xb, __hip_bfloat16* __restrict__ wt,
    __hip_bfloat16* __restrict__ wot, float* __restrict__ bcat) {
  __shared__ float tile[64][66];
  const int bid = blockIdx.x;
  const int tid = threadIdx.x;
  if (bid < 2048) {                    // cast x -> bf16, 8 elems/thread
    const int i = bid * 256 + tid;
    const float4 a = ((const float4*)x)[2 * i];
    const float4 b = ((const float4*)x)[2 * i + 1];
    union { ushort u[8]; short8 v; } o;
    __hip_bfloat16 h;
    h = __float2bfloat16(a.x); o.u[0] = *(ushort*)&h;
    h = __float2bfloat16(a.y); o.u[1] = *(ushort*)&h;
    h = __float2bfloat16(a.z); o.u[2] = *(ushort*)&h;
    h = __float2bfloat16(a.w); o.u[3] = *(ushort*)&h;
    h = __float2bfloat16(b.x); o.u[4] = *(ushort*)&h;
    h = __float2bfloat16(b.y); o.u[5] = *(ushort*)&h;
    h = __float2bfloat16(b.z); o.u[6] = *(ushort*)&h;
    h = __float2bfloat16(b.w); o.u[7] = *(ushort*)&h;
    ((short8*)xb)[i] = o.v;
  } else if (bid < 3072) {             // Wq^T [2048x2048]
    const int lid = bid - 2048;
    tcast_body(Wq, wt, 2048, 2048, lid & 31, lid >> 5, tid, tile);
  } else if (bid < 3328) {             // Wk^T [2048x512] -> wt + 2048*2048
    const int lid = bid - 3072;
    tcast_body(Wk, wt + (size_t)2048 * 2048, 512, 2048, lid & 7, lid >> 3, tid, tile);
  } else if (bid < 3584) {             // Wv^T -> wt + 2560*2048
    const int lid = bid - 3328;
    tcast_body(Wv, wt + (size_t)2560 * 2048, 512, 2048, lid & 7, lid >> 3, tid, tile);
  } else if (bid < 4608) {             // Wo^T [2048x2048] -> wot
    const int lid = bid - 3584;
    tcast_body(Wo, wot, 2048, 2048, lid & 31, lid >> 5, tid, tile);
  } else {                             // bias concat
    for (int i = tid; i < 3072; i += 256)
      bcat[i] = (i < 2048) ? bq[i] : ((i < 2560) ? bk[i - 2048] : bv[i - 2560]);
  }
}

// ---------------------------------------------------------------------------
// bf16 MFMA GEMM: C = A[M][K] @ Bt[N][K]^T + bias.
// NEW (R7): 2-phase double-buffered staging — STAGE(t+1) issued BEFORE
// compute(t), one barrier per K-step (T3-minimum). HBM latency hides under
// the 32 MFMAs instead of being serially exposed at 1-2 blocks/CU.
// ---------------------------------------------------------------------------
template <typename OutT>
__global__ __launch_bounds__(256) void gemm_mfma_bt(
    const __hip_bfloat16* __restrict__ A, const __hip_bfloat16* __restrict__ Bt,
    const float* __restrict__ bias, OutT* __restrict__ C, int K, int ldc) {
  __shared__ alignas(16) short As[2][128 * 64];
  __shared__ alignas(16) short Bs[2][128 * 64];
  const int tid = threadIdx.x;
  const int lane = tid & 63;
  const int w = tid >> 6;
  const int wr = w >> 1, wc = w & 1;
  const int bm = blockIdx.y * 128, bn = blockIdx.x * 128;

  floatx4 acc[4][4];
#pragma unroll
  for (int m = 0; m < 4; ++m)
#pragma unroll
    for (int n = 0; n < 4; ++n) acc[m][n] = floatx4{0.f, 0.f, 0.f, 0.f};

  const int frag_kb = (lane >> 4) * 16;
  const int srow8 = lane >> 3;
  const int sbyte = (lane & 7) * 16;

  auto stage = [&](int buf, int k0) {
#pragma unroll
    for (int i = 0; i < 4; ++i) {
      const int r = w * 32 + i * 8 + srow8;
      const int gcb = sbyte ^ ((r & 7) << 4);
      gload_lds16((const char*)(A + (size_t)(bm + r) * K + k0) + gcb,
                  (char*)(As[buf]) + (w * 32 + i * 8) * 128);
      gload_lds16((const char*)(Bt + (size_t)(bn + r) * K + k0) + gcb,
                  (char*)(Bs[buf]) + (w * 32 + i * 8) * 128);
    }
  };

  stage(0, 0);
  __syncthreads();                 // compiler drains vmcnt before s_barrier
  int cur = 0;
  for (int k0 = 0; k0 < K; k0 += 64) {
    if (k0 + 64 < K) stage(cur ^ 1, k0 + 64);   // prefetch next tile
#pragma unroll
    for (int h = 0; h < 2; ++h) {
      short8 af[4], bf[4];
      const int kb = h * 64 + frag_kb;
#pragma unroll
      for (int m = 0; m < 4; ++m) {
        const int ar = wr * 64 + m * 16 + (lane & 15);
        af[m] = *(const short8*)((const char*)(As[cur]) + ar * 128 + (kb ^ ((ar & 7) << 4)));
      }
#pragma unroll
      for (int n = 0; n < 4; ++n) {
        const int br = wc * 64 + n * 16 + (lane & 15);
        bf[n] = *(const short8*)((const char*)(Bs[cur]) + br * 128 + (kb ^ ((br & 7) << 4)));
      }
#pragma unroll
      for (int m = 0; m < 4; ++m)
#pragma unroll
        for (int n = 0; n < 4; ++n)
          acc[m][n] = __builtin_amdgcn_mfma_f32_16x16x32_bf16(af[m], bf[n], acc[m][n], 0, 0, 0);
    }
    __syncthreads();               // prefetched tile complete + reads done
    cur ^= 1;
  }

  const int col_l = lane & 15;
  const int row_l = (lane >> 4) * 4;
#pragma unroll
  for (int n = 0; n < 4; ++n) {
    const int col = bn + wc * 64 + n * 16 + col_l;
    const float bv = bias[col];
#pragma unroll
    for (int m = 0; m < 4; ++m) {
      const int row0 = bm + wr * 64 + m * 16 + row_l;
#pragma unroll
      for (int r2 = 0; r2 < 4; ++r2) {
        const float v = acc[m][n][r2] + bv;
        if constexpr (sizeof(OutT) == 2)
          C[(size_t)(row0 + r2) * ldc + col] = __float2bfloat16(v);
        else
          C[(size_t)(row0 + r2) * ldc + col] = v;
      }
    }
  }
}

// ---------------------------------------------------------------------------
// RoPE in-place on bf16 qkv. Q heads scaled by 0.125 (exact in bf16).
// ---------------------------------------------------------------------------
__global__ __launch_bounds__(256) void rope_kernel(__hip_bfloat16* __restrict__ qkv,
                                                   const float* __restrict__ freqs) {
  const int idx = blockIdx.x * 256 + threadIdx.x;
  const int i = idx & 31;
  const int h = (idx >> 5) % 40;
  const int t = idx / (40 * 32);
  const int base = (h < 32) ? h * HD : DM + (h - 32) * HD;
  __hip_bfloat16* p = qkv + (size_t)t * QKV_LD + base;
  const float f = freqs[t * 32 + i];
  float s, c;
  sincosf(f, &s, &c);
  const float x1 = __bfloat162float(p[i]);
  const float x2 = __bfloat162float(p[i + 32]);
  float r1 = x1 * c - x2 * s;
  float r2 = x1 * s + x2 * c;
  if (h < 32) { r1 *= 0.125f; r2 *= 0.125f; }
  p[i]      = __float2bfloat16(r1);
  p[i + 32] = __float2bfloat16(r2);
}

// ---------------------------------------------------------------------------
// V^T precompute: qkv V-cols [2048 t][512 (kvh,d)] -> vt [512][2048 t].
// ---------------------------------------------------------------------------
__global__ __launch_bounds__(256) void transpose_v_kernel(
    const __hip_bfloat16* __restrict__ qkv, __hip_bfloat16* __restrict__ vt) {
  __shared__ short tile[64][66];
  const int c0 = blockIdx.x * 64;
  const int t0 = blockIdx.y * 64;
  const int c = threadIdx.x & 63;
  const int r0 = threadIdx.x >> 6;
#pragma unroll
  for (int s = 0; s < 16; ++s) {
    int r = r0 + 4 * s;
    tile[r][c] = *(const short*)(qkv + (size_t)(t0 + r) * QKV_LD + DM + NKV * HD + c0 + c);
  }
  __syncthreads();
#pragma unroll
  for (int s = 0; s < 16; ++s) {
    int r = r0 + 4 * s;
    *(short*)(vt + (size_t)(c0 + r) * T_CTX + t0 + c) = tile[c][r];
  }
}

// ---------------------------------------------------------------------------
// MFMA flash attention with KV-split (R7). Block = (head-pair, chunk).
// Per hp (16): 48 chunks -> grid 768 (3 blocks/CU, near-uniform 8-16 tiles).
//   w48 <  32: split chunk of qb = 31-(w48>>1), half = w48&1
//              half0 = tiles [0,h), half1 = [h, qb+1), h = (qb+2)/2
//              -> writes partials (bf16 O unnormalized, f32 m/l)
//   w48 >= 32: unsplit qb = 15-(w48-32), tiles [0, qb+1) -> direct output
// 4 waves x 16 rows x 2 heads; defer-max softmax (THR=8); fragment
// conventions as verified R4-R6.
// ---------------------------------------------------------------------------
__global__ __launch_bounds__(256) void attn_mfma_kernel(
    const __hip_bfloat16* __restrict__ qkv, const __hip_bfloat16* __restrict__ vtg,
    __hip_bfloat16* __restrict__ O, __hip_bfloat16* __restrict__ Opart,
    float* __restrict__ mlpart) {
  const int bid = blockIdx.x;
  const int hp = bid / 48;
  const int w48 = bid % 48;
  int qb, t0, t1, half;
  bool split;
  if (w48 < 32) {
    qb = 31 - (w48 >> 1);
    half = w48 & 1;
    const int h = (qb + 2) >> 1;
    split = true;
    t0 = half ? h : 0;
    t1 = half ? (qb + 1) : h;
  } else {
    qb = 15 - (w48 - 32);
    half = 0; split = false;
    t0 = 0; t1 = qb + 1;
  }
  const int h0 = hp * 2;
  const int kvh = h0 >> 2;
  const int tid = threadIdx.x;
  const int lane = tid & 63;
  const int w = tid >> 6;
  const int l15 = lane & 15;
  const int lg = lane >> 4;
  const int qbase = qb * 64 + w * 16;

  __shared__ alignas(16) char Ks[64 * 128];
  __shared__ alignas(16) char Vts[64 * 128];
  __shared__ alignas(16) char Ps[4][2][16 * 128];

  short8 qf[2][2];
#pragma unroll
  for (int hh = 0; hh < 2; ++hh)
#pragma unroll
    for (int kh = 0; kh < 2; ++kh)
      qf[hh][kh] = *(const short8*)(qkv + (size_t)(qbase + l15) * QKV_LD +
                                    (h0 + hh) * HD + kh * 32 + lg * 8);

  floatx4 o_acc[2][4];
  float mrow[2][4], lrow[2][4];
#pragma unroll
  for (int hh = 0; hh < 2; ++hh)
#pragma unroll
    for (int n = 0; n < 4; ++n) o_acc[hh][n] = floatx4{0.f, 0.f, 0.f, 0.f};
#pragma unroll
  for (int hh = 0; hh < 2; ++hh)
#pragma unroll
    for (int r = 0; r < 4; ++r) { mrow[hh][r] = -INFINITY; lrow[hh][r] = 0.f; }

  const __hip_bfloat16* Kg = qkv + DM + kvh * HD;
  const int srow8 = lane >> 3;
  const int sbyte = (lane & 7) * 16;

  for (int kt = t0; kt < t1; ++kt) {
    const int s0 = kt * 64;
    __syncthreads();
#pragma unroll
    for (int i = 0; i < 2; ++i) {
      const int r = w * 16 + i * 8 + srow8;
      const int gcb = sbyte ^ ((r & 7) << 4);
      gload_lds16((const char*)(Kg + (size_t)(s0 + r) * QKV_LD) + gcb,
                  Ks + (w * 16 + i * 8) * 128);
      gload_lds16((const char*)(vtg + (size_t)(kvh * 64 + r) * T_CTX + s0) + gcb,
                  Vts + (w * 16 + i * 8) * 128);
    }
    __syncthreads();

    if (s0 > qbase + 15) continue;

    floatx4 sacc[2][4];
#pragma unroll
    for (int hh = 0; hh < 2; ++hh)
#pragma unroll
      for (int n = 0; n < 4; ++n) sacc[hh][n] = floatx4{0.f, 0.f, 0.f, 0.f};
#pragma unroll
    for (int kh = 0; kh < 2; ++kh) {
      short8 bf[4];
#pragma unroll
      for (int n = 0; n < 4; ++n) {
        const int kr = n * 16 + l15;
        bf[n] = *(const short8*)(Ks + kr * 128 + ((kh * 64 + lg * 16) ^ ((kr & 7) << 4)));
      }
#pragma unroll
      for (int hh = 0; hh < 2; ++hh)
#pragma unroll
        for (int n = 0; n < 4; ++n)
          sacc[hh][n] = __builtin_amdgcn_mfma_f32_16x16x32_bf16(qf[hh][kh], bf[n], sacc[hh][n], 0, 0, 0);
    }
    if (s0 + 63 > qbase) {
#pragma unroll
      for (int n = 0; n < 4; ++n)
#pragma unroll
        for (int r = 0; r < 4; ++r)
          if (s0 + n * 16 + l15 > qbase + lg * 4 + r) {
            sacc[0][n][r] = -INFINITY;
            sacc[1][n][r] = -INFINITY;
          }
    }
#pragma unroll
    for (int hh = 0; hh < 2; ++hh) {
#pragma unroll
      for (int r = 0; r < 4; ++r) {
        float t = fmaxf(fmaxf(sacc[hh][0][r], sacc[hh][1][r]),
                        fmaxf(sacc[hh][2][r], sacc[hh][3][r]));
        t = fmaxf(t, __shfl_xor(t, 1));
        t = fmaxf(t, __shfl_xor(t, 2));
        t = fmaxf(t, __shfl_xor(t, 4));
        t = fmaxf(t, __shfl_xor(t, 8));
        float mn = mrow[hh][r];
        if (t > mn + 8.f) {            // defer-max (T13)
          const float corr = __expf(mn - t);
          lrow[hh][r] *= corr;
#pragma unroll
          for (int n = 0; n < 4; ++n) o_acc[hh][n][r] *= corr;
          mn = t;
          mrow[hh][r] = t;
        }
        float pv[4];
        float ls = 0.f;
#pragma unroll
        for (int n = 0; n < 4; ++n) {
          pv[n] = __expf(sacc[hh][n][r] - mn);
          ls += pv[n];
        }
        ls += __shfl_xor(ls, 1);
        ls += __shfl_xor(ls, 2);
        ls += __shfl_xor(ls, 4);
        ls += __shfl_xor(ls, 8);
        lrow[hh][r] += ls;
        const int prow = lg * 4 + r;
#pragma unroll
        for (int n = 0; n < 4; ++n)
          *(__hip_bfloat16*)(Ps[w][hh] + prow * 128 +
                             (((n * 16 + l15) * 2) ^ ((prow & 7) << 4))) =
              __float2bfloat16(pv[n]);
      }
    }
#pragma unroll
    for (int kh = 0; kh < 2; ++kh) {
      short8 vf[4];
#pragma unroll
      for (int n = 0; n < 4; ++n) {
        const int vr = n * 16 + l15;
        vf[n] = *(const short8*)(Vts + vr * 128 + ((kh * 64 + lg * 16) ^ ((vr & 7) << 4)));
      }
#pragma unroll
      for (int hh = 0; hh < 2; ++hh) {
        const short8 pf = *(const short8*)(Ps[w][hh] + l15 * 128 +
                                           ((kh * 64 + lg * 16) ^ ((l15 & 7) << 4)));
#pragma unroll
        for (int n = 0; n < 4; ++n)
          o_acc[hh][n] = __builtin_amdgcn_mfma_f32_16x16x32_bf16(pf, vf[n], o_acc[hh][n], 0, 0, 0);
      }
    }
  }

  // --- epilogue ---
  if (!split) {
#pragma unroll
    for (int hh = 0; hh < 2; ++hh) {
      float inv[4];
#pragma unroll
      for (int r = 0; r < 4; ++r) inv[r] = 1.f / lrow[hh][r];
#pragma unroll
      for (int n = 0; n < 4; ++n)
#pragma unroll
        for (int r = 0; r < 4; ++r)
          O[(size_t)(qbase + lg * 4 + r) * DM + (h0 + hh) * HD + n * 16 + l15] =
              __float2bfloat16(o_acc[hh][n][r] * inv[r]);
    }
  } else {
#pragma unroll
    for (int hh = 0; hh < 2; ++hh) {
      const int u = (((h0 + hh) << 4) + (qb - 16)) * 2 + half;
#pragma unroll
      for (int n = 0; n < 4; ++n)
#pragma unroll
        for (int r = 0; r < 4; ++r)
          Opart[(size_t)u * 4096 + (w * 16 + lg * 4 + r) * 64 + n * 16 + l15] =
              __float2bfloat16(o_acc[hh][n][r]);
      if (l15 == 0) {
#pragma unroll
        for (int r = 0; r < 4; ++r) {
          mlpart[u * 128 + w * 16 + lg * 4 + r]      = mrow[hh][r];
          mlpart[u * 128 + 64 + w * 16 + lg * 4 + r] = lrow[hh][r];
        }
      }
    }
  }
}

// ---------------------------------------------------------------------------
// Combine the two KV-half partials for qb in [16,32): standard (m,l,O) merge.
// Grid (32 heads x 16 qbs) = 512 blocks; thread r = tid>>2, 16 cols each.
// ---------------------------------------------------------------------------
__global__ __launch_bounds__(256) void combine_kernel(
    const __hip_bfloat16* __restrict__ Opart, const float* __restrict__ mlpart,
    __hip_bfloat16* __restrict__ O) {
  const int head = blockIdx.x >> 4;
  const int sqb = blockIdx.x & 15;       // qb = 16 + sqb
  const int tid = threadIdx.x;
  const int r = tid >> 2;
  const int c0 = (tid & 3) * 16;
  const int u0 = (((head << 4) + sqb) << 1);
  const float m0 = mlpart[u0 * 128 + r];
  const float l0 = mlpart[u0 * 128 + 64 + r];
  const float m1 = mlpart[(u0 + 1) * 128 + r];
  const float l1 = mlpart[(u0 + 1) * 128 + 64 + r];
  const float M = fmaxf(m0, m1);
  const float a0 = __expf(m0 - M), a1 = __expf(m1 - M);
  const float inv = 1.f / (a0 * l0 + a1 * l1);
  const __hip_bfloat16* p0 = Opart + (size_t)u0 * 4096 + r * 64 + c0;
  const __hip_bfloat16* p1 = Opart + (size_t)(u0 + 1) * 4096 + r * 64 + c0;
  __hip_bfloat16* op = O + (size_t)((16 + sqb) * 64 + r) * DM + head * HD + c0;
#pragma unroll
  for (int j = 0; j < 16; ++j)
    op[j] = __float2bfloat16(
        (a0 * __bfloat162float(p0[j]) + a1 * __bfloat162float(p1[j])) * inv);
}

// ---------------------------------------------------------------------------
extern "C" void kernel_launch(void* const* d_in, const int* in_sizes, int n_in,
                              void* d_out, int out_size, void* d_ws, size_t ws_size,
                              hipStream_t stream) {
  const float* x     = (const float*)d_in[0];
  const float* Wq    = (const float*)d_in[1];
  const float* bq    = (const float*)d_in[2];
  const float* Wk    = (const float*)d_in[3];
  const float* bk    = (const float*)d_in[4];
  const float* Wv    = (const float*)d_in[5];
  const float* bv    = (const float*)d_in[6];
  const float* Wo    = (const float*)d_in[7];
  const float* bo    = (const float*)d_in[8];
  const float* freqs = (const float*)d_in[9];
  float* out = (float*)d_out;

  // ws layout (peak 44.6 MB):
  //   [0)           qkv   bf16 [2048][3072]          12,582,912 B
  //   [12,582,912)  wt    bf16 [3072][2048] QKV^T    12,582,912 B -> obuf after QKV GEMM
  //   [25,165,824)  xb    bf16 [2048][2048]           8,388,608 B -> Opart after QKV GEMM
  //   [33,554,432)  wot   bf16 [2048][2048] Wo^T      8,388,608 B
  //   [41,943,040)  vt    bf16 [512][2048]  V^T       2,097,152 B
  //   [44,040,192)  bcat  f32 [3072]                     12,288 B
  //   [44,052,480)  ml    f32 [1024][128]               524,288 B
  char* ws = (char*)d_ws;
  __hip_bfloat16* qkv   = (__hip_bfloat16*)ws;
  __hip_bfloat16* wt    = (__hip_bfloat16*)(ws + 12582912);
  __hip_bfloat16* obuf  = wt;   // alias: wt dead after QKV GEMM
  __hip_bfloat16* xb    = (__hip_bfloat16*)(ws + 25165824);
  __hip_bfloat16* opart = xb;   // alias: xb dead after QKV GEMM (1024*4096 bf16)
  __hip_bfloat16* wot   = (__hip_bfloat16*)(ws + 33554432);
  __hip_bfloat16* vt    = (__hip_bfloat16*)(ws + 41943040);
  float*          bcat  = (float*)(ws + 44040192);
  float*          ml    = (float*)(ws + 44052480);

  const dim3 blk(256);

  prep_kernel<<<dim3(4609), blk, 0, stream>>>(x, Wq, Wk, Wv, Wo, bq, bk, bv,
                                              xb, wt, wot, bcat);

  gemm_mfma_bt<__hip_bfloat16><<<dim3(3072 / 128, 2048 / 128), blk, 0, stream>>>(
      xb, wt, bcat, qkv, DM, QKV_LD);

  rope_kernel<<<(T_CTX * 40 * 32) / 256, blk, 0, stream>>>(qkv, freqs);

  transpose_v_kernel<<<dim3(8, 32), blk, 0, stream>>>(qkv, vt);

  // KV-split flash attention (768 blocks) + combine for split rows
  attn_mfma_kernel<<<dim3(16 * 48), blk, 0, stream>>>(qkv, vt, obuf, opart, ml);
  combine_kernel<<<dim3(512), blk, 0, stream>>>(opart, ml, obuf);

  gemm_mfma_bt<float><<<dim3(2048 / 128, 2048 / 128), blk, 0, stream>>>(
      obuf, wot, bo, out, DM, DM);
}

// Round 8
// 267.841 us; speedup vs baseline: 1.2891x; 1.1276x over previous
//
#include <hip/hip_runtime.h>
#include <hip/hip_bf16.h>
#include <math.h>

#define T_CTX 2048
#define DM    2048
#define NQ    32
#define NKV   8
#define HD    64
#define QKV_LD 3072   // fused [T][Q(2048) | K(512) | V(512)] bf16

typedef __attribute__((ext_vector_type(8))) short short8;     // 8 bf16 = 4 VGPR
typedef __attribute__((ext_vector_type(4))) short short4v;    // 4 bf16 = 8B
typedef __attribute__((ext_vector_type(4))) float floatx4;    // MFMA acc

// global -> LDS direct copy, 16B/lane. LDS dest wave-uniform base (HW: lane i
// writes base + i*16); global src per-lane, carries the inverse swizzle
// (rule #21: linear LDS, pre-swizzled source, swizzled read).
__device__ __forceinline__ void gload_lds16(const void* g, void* l) {
  __builtin_amdgcn_global_load_lds(
      (const __attribute__((address_space(1))) void*)g,
      (__attribute__((address_space(3))) void*)l, 16, 0, 0);
}

// ---------------------------------------------------------------------------
// Fused prep: x cast (blocks 0..2047), Wq^T (2048..3071), Wk^T (3072..3327),
// Wv^T (3328..3583), Wo^T (3584..4607), bias concat (4608). One launch.
// ---------------------------------------------------------------------------
__device__ __forceinline__ void tcast_body(const float* __restrict__ src,
                                           __hip_bfloat16* __restrict__ dst,
                                           int Ncols, int Krows, int bx, int by,
                                           int tid, float (*tile)[66]) {
  const int n0 = bx * 64, k0 = by * 64;
  const int c = tid & 63, r0 = tid >> 6;
#pragma unroll
  for (int s = 0; s < 16; ++s) {
    int r = r0 + 4 * s;
    tile[r][c] = src[(size_t)(k0 + r) * Ncols + n0 + c];
  }
  __syncthreads();
#pragma unroll
  for (int s = 0; s < 16; ++s) {
    int r = r0 + 4 * s;
    dst[(size_t)(n0 + r) * Krows + k0 + c] = __float2bfloat16(tile[c][r]);
  }
}

__global__ __launch_bounds__(256) void prep_kernel(
    const float* __restrict__ x, const float* __restrict__ Wq,
    const float* __restrict__ Wk, const float* __restrict__ Wv,
    const float* __restrict__ Wo, const float* __restrict__ bq,
    const float* __restrict__ bk, const float* __restrict__ bv,
    __hip_bfloat16* __restrict__ xb, __hip_bfloat16* __restrict__ wt,
    __hip_bfloat16* __restrict__ wot, float* __restrict__ bcat) {
  __shared__ float tile[64][66];
  const int bid = blockIdx.x;
  const int tid = threadIdx.x;
  if (bid < 2048) {                    // cast x -> bf16, 8 elems/thread
    const int i = bid * 256 + tid;
    const float4 a = ((const float4*)x)[2 * i];
    const float4 b = ((const float4*)x)[2 * i + 1];
    union { ushort u[8]; short8 v; } o;
    __hip_bfloat16 h;
    h = __float2bfloat16(a.x); o.u[0] = *(ushort*)&h;
    h = __float2bfloat16(a.y); o.u[1] = *(ushort*)&h;
    h = __float2bfloat16(a.z); o.u[2] = *(ushort*)&h;
    h = __float2bfloat16(a.w); o.u[3] = *(ushort*)&h;
    h = __float2bfloat16(b.x); o.u[4] = *(ushort*)&h;
    h = __float2bfloat16(b.y); o.u[5] = *(ushort*)&h;
    h = __float2bfloat16(b.z); o.u[6] = *(ushort*)&h;
    h = __float2bfloat16(b.w); o.u[7] = *(ushort*)&h;
    ((short8*)xb)[i] = o.v;
  } else if (bid < 3072) {             // Wq^T [2048x2048]
    const int lid = bid - 2048;
    tcast_body(Wq, wt, 2048, 2048, lid & 31, lid >> 5, tid, tile);
  } else if (bid < 3328) {             // Wk^T [2048x512] -> wt + 2048*2048
    const int lid = bid - 3072;
    tcast_body(Wk, wt + (size_t)2048 * 2048, 512, 2048, lid & 7, lid >> 3, tid, tile);
  } else if (bid < 3584) {             // Wv^T -> wt + 2560*2048
    const int lid = bid - 3328;
    tcast_body(Wv, wt + (size_t)2560 * 2048, 512, 2048, lid & 7, lid >> 3, tid, tile);
  } else if (bid < 4608) {             // Wo^T [2048x2048] -> wot
    const int lid = bid - 3584;
    tcast_body(Wo, wot, 2048, 2048, lid & 31, lid >> 5, tid, tile);
  } else {                             // bias concat
    for (int i = tid; i < 3072; i += 256)
      bcat[i] = (i < 2048) ? bq[i] : ((i < 2560) ? bk[i - 2048] : bv[i - 2560]);
  }
}

// ---------------------------------------------------------------------------
// bf16 MFMA GEMM (verified R3-R7): C = A[M][K] @ Bt[N][K]^T + bias.
// 2-phase double-buffered global_load_lds staging.
// ---------------------------------------------------------------------------
template <typename OutT>
__global__ __launch_bounds__(256) void gemm_mfma_bt(
    const __hip_bfloat16* __restrict__ A, const __hip_bfloat16* __restrict__ Bt,
    const float* __restrict__ bias, OutT* __restrict__ C, int K, int ldc) {
  __shared__ alignas(16) short As[2][128 * 64];
  __shared__ alignas(16) short Bs[2][128 * 64];
  const int tid = threadIdx.x;
  const int lane = tid & 63;
  const int w = tid >> 6;
  const int wr = w >> 1, wc = w & 1;
  const int bm = blockIdx.y * 128, bn = blockIdx.x * 128;

  floatx4 acc[4][4];
#pragma unroll
  for (int m = 0; m < 4; ++m)
#pragma unroll
    for (int n = 0; n < 4; ++n) acc[m][n] = floatx4{0.f, 0.f, 0.f, 0.f};

  const int frag_kb = (lane >> 4) * 16;
  const int srow8 = lane >> 3;
  const int sbyte = (lane & 7) * 16;

  auto stage = [&](int buf, int k0) {
#pragma unroll
    for (int i = 0; i < 4; ++i) {
      const int r = w * 32 + i * 8 + srow8;
      const int gcb = sbyte ^ ((r & 7) << 4);
      gload_lds16((const char*)(A + (size_t)(bm + r) * K + k0) + gcb,
                  (char*)(As[buf]) + (w * 32 + i * 8) * 128);
      gload_lds16((const char*)(Bt + (size_t)(bn + r) * K + k0) + gcb,
                  (char*)(Bs[buf]) + (w * 32 + i * 8) * 128);
    }
  };

  stage(0, 0);
  __syncthreads();
  int cur = 0;
  for (int k0 = 0; k0 < K; k0 += 64) {
    if (k0 + 64 < K) stage(cur ^ 1, k0 + 64);
#pragma unroll
    for (int h = 0; h < 2; ++h) {
      short8 af[4], bf[4];
      const int kb = h * 64 + frag_kb;
#pragma unroll
      for (int m = 0; m < 4; ++m) {
        const int ar = wr * 64 + m * 16 + (lane & 15);
        af[m] = *(const short8*)((const char*)(As[cur]) + ar * 128 + (kb ^ ((ar & 7) << 4)));
      }
#pragma unroll
      for (int n = 0; n < 4; ++n) {
        const int br = wc * 64 + n * 16 + (lane & 15);
        bf[n] = *(const short8*)((const char*)(Bs[cur]) + br * 128 + (kb ^ ((br & 7) << 4)));
      }
#pragma unroll
      for (int m = 0; m < 4; ++m)
#pragma unroll
        for (int n = 0; n < 4; ++n)
          acc[m][n] = __builtin_amdgcn_mfma_f32_16x16x32_bf16(af[m], bf[n], acc[m][n], 0, 0, 0);
    }
    __syncthreads();
    cur ^= 1;
  }

  const int col_l = lane & 15;
  const int row_l = (lane >> 4) * 4;
#pragma unroll
  for (int n = 0; n < 4; ++n) {
    const int col = bn + wc * 64 + n * 16 + col_l;
    const float bv = bias[col];
#pragma unroll
    for (int m = 0; m < 4; ++m) {
      const int row0 = bm + wr * 64 + m * 16 + row_l;
#pragma unroll
      for (int r2 = 0; r2 < 4; ++r2) {
        const float v = acc[m][n][r2] + bv;
        if constexpr (sizeof(OutT) == 2)
          C[(size_t)(row0 + r2) * ldc + col] = __float2bfloat16(v);
        else
          C[(size_t)(row0 + r2) * ldc + col] = v;
      }
    }
  }
}

// ---------------------------------------------------------------------------
// RoPE in-place on bf16 qkv. Q heads scaled by 0.125 (exact in bf16).
// ---------------------------------------------------------------------------
__global__ __launch_bounds__(256) void rope_kernel(__hip_bfloat16* __restrict__ qkv,
                                                   const float* __restrict__ freqs) {
  const int idx = blockIdx.x * 256 + threadIdx.x;
  const int i = idx & 31;
  const int h = (idx >> 5) % 40;
  const int t = idx / (40 * 32);
  const int base = (h < 32) ? h * HD : DM + (h - 32) * HD;
  __hip_bfloat16* p = qkv + (size_t)t * QKV_LD + base;
  const float f = freqs[t * 32 + i];
  float s, c;
  sincosf(f, &s, &c);
  const float x1 = __bfloat162float(p[i]);
  const float x2 = __bfloat162float(p[i + 32]);
  float r1 = x1 * c - x2 * s;
  float r2 = x1 * s + x2 * c;
  if (h < 32) { r1 *= 0.125f; r2 *= 0.125f; }
  p[i]      = __float2bfloat16(r1);
  p[i + 32] = __float2bfloat16(r2);
}

// ---------------------------------------------------------------------------
// V^T precompute: qkv V-cols [2048 t][512 (kvh,d)] -> vt [512][2048 t].
// ---------------------------------------------------------------------------
__global__ __launch_bounds__(256) void transpose_v_kernel(
    const __hip_bfloat16* __restrict__ qkv, __hip_bfloat16* __restrict__ vt) {
  __shared__ short tile[64][66];
  const int c0 = blockIdx.x * 64;
  const int t0 = blockIdx.y * 64;
  const int c = threadIdx.x & 63;
  const int r0 = threadIdx.x >> 6;
#pragma unroll
  for (int s = 0; s < 16; ++s) {
    int r = r0 + 4 * s;
    tile[r][c] = *(const short*)(qkv + (size_t)(t0 + r) * QKV_LD + DM + NKV * HD + c0 + c);
  }
  __syncthreads();
#pragma unroll
  for (int s = 0; s < 16; ++s) {
    int r = r0 + 4 * s;
    *(short*)(vt + (size_t)(c0 + r) * T_CTX + t0 + c) = tile[c][r];
  }
}

// ---------------------------------------------------------------------------
// MFMA flash attention (R8): KV-split grid as R7 (16 hp x 48 chunks).
// NEW: (1) swapped QK^T — sacc = mfma(K-frag, Q-frag) gives S^T: lane owns the
//      full 64-k slice of q-row lane&15 (16 scores in-reg); softmax reduce =
//      in-reg tree + 2 shfl_xor (was 8 rows x 8 shfls). Fragments unchanged.
//      (2) double-buffered K/V staging: stage(t+1) before compute(t), one
//      barrier per tile. (3) setprio around MFMA clusters.
// m/l are per-lane scalars for q-row lane&15; o_acc rows are lg*4+r, so
// rescale/epilogue broadcast via __shfl(x, lg*4+r).
// ---------------------------------------------------------------------------
__global__ __launch_bounds__(256) void attn_mfma_kernel(
    const __hip_bfloat16* __restrict__ qkv, const __hip_bfloat16* __restrict__ vtg,
    __hip_bfloat16* __restrict__ O, __hip_bfloat16* __restrict__ Opart,
    float* __restrict__ mlpart) {
  const int bid = blockIdx.x;
  const int hp = bid / 48;
  const int w48 = bid % 48;
  int qb, t0, t1, half;
  bool split;
  if (w48 < 32) {
    qb = 31 - (w48 >> 1);
    half = w48 & 1;
    const int h = (qb + 2) >> 1;
    split = true;
    t0 = half ? h : 0;
    t1 = half ? (qb + 1) : h;
  } else {
    qb = 15 - (w48 - 32);
    half = 0; split = false;
    t0 = 0; t1 = qb + 1;
  }
  const int h0 = hp * 2;
  const int kvh = h0 >> 2;
  const int tid = threadIdx.x;
  const int lane = tid & 63;
  const int w = tid >> 6;
  const int l15 = lane & 15;
  const int lg = lane >> 4;
  const int qbase = qb * 64 + w * 16;

  __shared__ alignas(16) char Ks[2][64 * 128];
  __shared__ alignas(16) char Vts[2][64 * 128];
  __shared__ alignas(16) char Ps[4][2][16 * 128];

  short8 qf[2][2];
#pragma unroll
  for (int hh = 0; hh < 2; ++hh)
#pragma unroll
    for (int kh = 0; kh < 2; ++kh)
      qf[hh][kh] = *(const short8*)(qkv + (size_t)(qbase + l15) * QKV_LD +
                                    (h0 + hh) * HD + kh * 32 + lg * 8);

  floatx4 o_acc[2][4];
  float mrow[2], lrow[2];
#pragma unroll
  for (int hh = 0; hh < 2; ++hh) {
#pragma unroll
    for (int n = 0; n < 4; ++n) o_acc[hh][n] = floatx4{0.f, 0.f, 0.f, 0.f};
    mrow[hh] = -INFINITY;
    lrow[hh] = 0.f;
  }

  const __hip_bfloat16* Kg = qkv + DM + kvh * HD;
  const int srow8 = lane >> 3;
  const int sbyte = (lane & 7) * 16;

  auto stage = [&](int buf, int kt) {
    const int s0 = kt * 64;
#pragma unroll
    for (int i = 0; i < 2; ++i) {
      const int r = w * 16 + i * 8 + srow8;
      const int gcb = sbyte ^ ((r & 7) << 4);
      gload_lds16((const char*)(Kg + (size_t)(s0 + r) * QKV_LD) + gcb,
                  Ks[buf] + (w * 16 + i * 8) * 128);
      gload_lds16((const char*)(vtg + (size_t)(kvh * 64 + r) * T_CTX + s0) + gcb,
                  Vts[buf] + (w * 16 + i * 8) * 128);
    }
  };

  stage(0, t0);
  __syncthreads();
  int cur = 0;

  for (int kt = t0; kt < t1; ++kt) {
    if (kt + 1 < t1) stage(cur ^ 1, kt + 1);   // prefetch next tile
    const int s0 = kt * 64;
    if (s0 <= qbase + 15) {
      // --- QK^T swapped: sacc[hh][n] = S^T, k = s0+n*16+lg*4+r, q = qbase+l15
      floatx4 sacc[2][4];
#pragma unroll
      for (int hh = 0; hh < 2; ++hh)
#pragma unroll
        for (int n = 0; n < 4; ++n) sacc[hh][n] = floatx4{0.f, 0.f, 0.f, 0.f};
#pragma unroll
      for (int kh = 0; kh < 2; ++kh) {
        short8 bf[4];
#pragma unroll
        for (int n = 0; n < 4; ++n) {
          const int kr = n * 16 + l15;
          bf[n] = *(const short8*)(Ks[cur] + kr * 128 + ((kh * 64 + lg * 16) ^ ((kr & 7) << 4)));
        }
        __builtin_amdgcn_s_setprio(1);
#pragma unroll
        for (int hh = 0; hh < 2; ++hh)
#pragma unroll
          for (int n = 0; n < 4; ++n)
            sacc[hh][n] = __builtin_amdgcn_mfma_f32_16x16x32_bf16(bf[n], qf[hh][kh], sacc[hh][n], 0, 0, 0);
        __builtin_amdgcn_s_setprio(0);
      }
      // --- causal mask: k > q ---
      if (s0 + 63 > qbase) {
#pragma unroll
        for (int n = 0; n < 4; ++n)
#pragma unroll
          for (int r = 0; r < 4; ++r)
            if (s0 + n * 16 + lg * 4 + r > qbase + l15) {
              sacc[0][n][r] = -INFINITY;
              sacc[1][n][r] = -INFINITY;
            }
      }
      // --- softmax: per-lane row (q = qbase+l15), in-reg + 2 shfls ---
#pragma unroll
      for (int hh = 0; hh < 2; ++hh) {
        float t01 = fmaxf(fmaxf(sacc[hh][0][0], sacc[hh][0][1]),
                          fmaxf(sacc[hh][0][2], sacc[hh][0][3]));
        float t23 = fmaxf(fmaxf(sacc[hh][1][0], sacc[hh][1][1]),
                          fmaxf(sacc[hh][1][2], sacc[hh][1][3]));
        float t45 = fmaxf(fmaxf(sacc[hh][2][0], sacc[hh][2][1]),
                          fmaxf(sacc[hh][2][2], sacc[hh][2][3]));
        float t67 = fmaxf(fmaxf(sacc[hh][3][0], sacc[hh][3][1]),
                          fmaxf(sacc[hh][3][2], sacc[hh][3][3]));
        float tmax = fmaxf(fmaxf(t01, t23), fmaxf(t45, t67));
        tmax = fmaxf(tmax, __shfl_xor(tmax, 16));
        tmax = fmaxf(tmax, __shfl_xor(tmax, 32));
        float mn = mrow[hh];
        if (__any(tmax > mn + 8.f)) {        // defer-max (T13)
          const float mnew = fmaxf(mn, tmax);
          const float corr = __expf(mn - mnew);   // -inf first tile -> 0
          lrow[hh] *= corr;
          float cb[4];
#pragma unroll
          for (int r = 0; r < 4; ++r) cb[r] = __shfl(corr, lg * 4 + r);
#pragma unroll
          for (int n = 0; n < 4; ++n)
#pragma unroll
            for (int r = 0; r < 4; ++r) o_acc[hh][n][r] *= cb[r];
          mrow[hh] = mnew;
          mn = mnew;
        }
        float ls = 0.f;
        float pv[4][4];
#pragma unroll
        for (int n = 0; n < 4; ++n)
#pragma unroll
          for (int r = 0; r < 4; ++r) {
            pv[n][r] = __expf(sacc[hh][n][r] - mn);   // masked -inf -> 0
            ls += pv[n][r];
          }
        ls += __shfl_xor(ls, 16);
        ls += __shfl_xor(ls, 32);
        lrow[hh] += ls;
        // P write: lane holds P[q=l15][k=n*16+lg*4+r] -> 4x ds_write_b64
#pragma unroll
        for (int n = 0; n < 4; ++n) {
          short4v pk;
#pragma unroll
          for (int r = 0; r < 4; ++r) {
            __hip_bfloat16 hb = __float2bfloat16(pv[n][r]);
            pk[r] = *(short*)&hb;
          }
          *(short4v*)(Ps[w][hh] + l15 * 128 +
                      (((n * 16 + lg * 4) * 2) ^ ((l15 & 7) << 4))) = pk;
        }
      }
      // --- PV: O[16q][64d] += P @ V (same-wave P, no barrier) ---
#pragma unroll
      for (int kh = 0; kh < 2; ++kh) {
        short8 vf[4];
#pragma unroll
        for (int n = 0; n < 4; ++n) {
          const int vr = n * 16 + l15;
          vf[n] = *(const short8*)(Vts[cur] + vr * 128 + ((kh * 64 + lg * 16) ^ ((vr & 7) << 4)));
        }
        __builtin_amdgcn_s_setprio(1);
#pragma unroll
        for (int hh = 0; hh < 2; ++hh) {
          const short8 pf = *(const short8*)(Ps[w][hh] + l15 * 128 +
                                             ((kh * 64 + lg * 16) ^ ((l15 & 7) << 4)));
#pragma unroll
          for (int n = 0; n < 4; ++n)
            o_acc[hh][n] = __builtin_amdgcn_mfma_f32_16x16x32_bf16(pf, vf[n], o_acc[hh][n], 0, 0, 0);
        }
        __builtin_amdgcn_s_setprio(0);
      }
    }
    __syncthreads();   // next tile staged + all reads of cur done
    cur ^= 1;
  }

  // --- epilogue: o_acc rows lg*4+r; l lives in lane (row) -> shfl broadcast ---
  if (!split) {
#pragma unroll
    for (int hh = 0; hh < 2; ++hh) {
      float inv[4];
#pragma unroll
      for (int r = 0; r < 4; ++r) inv[r] = 1.f / __shfl(lrow[hh], lg * 4 + r);
#pragma unroll
      for (int n = 0; n < 4; ++n)
#pragma unroll
        for (int r = 0; r < 4; ++r)
          O[(size_t)(qbase + lg * 4 + r) * DM + (h0 + hh) * HD + n * 16 + l15] =
              __float2bfloat16(o_acc[hh][n][r] * inv[r]);
    }
  } else {
#pragma unroll
    for (int hh = 0; hh < 2; ++hh) {
      const int u = (((h0 + hh) << 4) + (qb - 16)) * 2 + half;
#pragma unroll
      for (int n = 0; n < 4; ++n)
#pragma unroll
        for (int r = 0; r < 4; ++r)
          Opart[(size_t)u * 4096 + (w * 16 + lg * 4 + r) * 64 + n * 16 + l15] =
              __float2bfloat16(o_acc[hh][n][r]);
      if (lane < 16) {
        // lane l15 holds (m,l) for row w*16 + l15
        mlpart[u * 128 + w * 16 + l15]      = mrow[hh];
        mlpart[u * 128 + 64 + w * 16 + l15] = lrow[hh];
      }
    }
  }
}

// ---------------------------------------------------------------------------
// Combine the two KV-half partials for qb in [16,32): standard (m,l,O) merge.
// ---------------------------------------------------------------------------
__global__ __launch_bounds__(256) void combine_kernel(
    const __hip_bfloat16* __restrict__ Opart, const float* __restrict__ mlpart,
    __hip_bfloat16* __restrict__ O) {
  const int head = blockIdx.x >> 4;
  const int sqb = blockIdx.x & 15;       // qb = 16 + sqb
  const int tid = threadIdx.x;
  const int r = tid >> 2;
  const int c0 = (tid & 3) * 16;
  const int u0 = (((head << 4) + sqb) << 1);
  const float m0 = mlpart[u0 * 128 + r];
  const float l0 = mlpart[u0 * 128 + 64 + r];
  const float m1 = mlpart[(u0 + 1) * 128 + r];
  const float l1 = mlpart[(u0 + 1) * 128 + 64 + r];
  const float M = fmaxf(m0, m1);
  const float a0 = __expf(m0 - M), a1 = __expf(m1 - M);
  const float inv = 1.f / (a0 * l0 + a1 * l1);
  const __hip_bfloat16* p0 = Opart + (size_t)u0 * 4096 + r * 64 + c0;
  const __hip_bfloat16* p1 = Opart + (size_t)(u0 + 1) * 4096 + r * 64 + c0;
  __hip_bfloat16* op = O + (size_t)((16 + sqb) * 64 + r) * DM + head * HD + c0;
#pragma unroll
  for (int j = 0; j < 16; ++j)
    op[j] = __float2bfloat16(
        (a0 * __bfloat162float(p0[j]) + a1 * __bfloat162float(p1[j])) * inv);
}

// ---------------------------------------------------------------------------
extern "C" void kernel_launch(void* const* d_in, const int* in_sizes, int n_in,
                              void* d_out, int out_size, void* d_ws, size_t ws_size,
                              hipStream_t stream) {
  const float* x     = (const float*)d_in[0];
  const float* Wq    = (const float*)d_in[1];
  const float* bq    = (const float*)d_in[2];
  const float* Wk    = (const float*)d_in[3];
  const float* bk    = (const float*)d_in[4];
  const float* Wv    = (const float*)d_in[5];
  const float* bv    = (const float*)d_in[6];
  const float* Wo    = (const float*)d_in[7];
  const float* bo    = (const float*)d_in[8];
  const float* freqs = (const float*)d_in[9];
  float* out = (float*)d_out;

  // ws layout (peak 44.6 MB):
  //   [0)           qkv   bf16 [2048][3072]          12,582,912 B
  //   [12,582,912)  wt    bf16 [3072][2048] QKV^T    12,582,912 B -> obuf after QKV GEMM
  //   [25,165,824)  xb    bf16 [2048][2048]           8,388,608 B -> Opart after QKV GEMM
  //   [33,554,432)  wot   bf16 [2048][2048] Wo^T      8,388,608 B
  //   [41,943,040)  vt    bf16 [512][2048]  V^T       2,097,152 B
  //   [44,040,192)  bcat  f32 [3072]                     12,288 B
  //   [44,052,480)  ml    f32 [1024][128]               524,288 B
  char* ws = (char*)d_ws;
  __hip_bfloat16* qkv   = (__hip_bfloat16*)ws;
  __hip_bfloat16* wt    = (__hip_bfloat16*)(ws + 12582912);
  __hip_bfloat16* obuf  = wt;   // alias: wt dead after QKV GEMM
  __hip_bfloat16* xb    = (__hip_bfloat16*)(ws + 25165824);
  __hip_bfloat16* opart = xb;   // alias: xb dead after QKV GEMM
  __hip_bfloat16* wot   = (__hip_bfloat16*)(ws + 33554432);
  __hip_bfloat16* vt    = (__hip_bfloat16*)(ws + 41943040);
  float*          bcat  = (float*)(ws + 44040192);
  float*          ml    = (float*)(ws + 44052480);

  const dim3 blk(256);

  prep_kernel<<<dim3(4609), blk, 0, stream>>>(x, Wq, Wk, Wv, Wo, bq, bk, bv,
                                              xb, wt, wot, bcat);

  gemm_mfma_bt<__hip_bfloat16><<<dim3(3072 / 128, 2048 / 128), blk, 0, stream>>>(
      xb, wt, bcat, qkv, DM, QKV_LD);

  rope_kernel<<<(T_CTX * 40 * 32) / 256, blk, 0, stream>>>(qkv, freqs);

  transpose_v_kernel<<<dim3(8, 32), blk, 0, stream>>>(qkv, vt);

  attn_mfma_kernel<<<dim3(16 * 48), blk, 0, stream>>>(qkv, vt, obuf, opart, ml);
  combine_kernel<<<dim3(512), blk, 0, stream>>>(opart, ml, obuf);

  gemm_mfma_bt<float><<<dim3(2048 / 128, 2048 / 128), blk, 0, stream>>>(
      obuf, wot, bo, out, DM, DM);
}